// Round 16
// baseline (289.234 us; speedup 1.0000x reference)
//
#include <hip/hip_runtime.h>
#include <cmath>

#define B_ 4
#define S_ 2048
#define D_ 768
#define H_ 12
#define HD_ 64
#define SCALE_ 0.125f
#define LOG2E_ 1.4426950408889634f
#define M_ 8192
#define NE_ 6291456ull   // B*S*D
#define BHS_ 98304ull    // B*H*S

typedef unsigned short ushortT;
typedef unsigned int u32;
typedef __attribute__((ext_vector_type(8))) __bf16 bf16x8;
typedef __attribute__((ext_vector_type(4))) float f32x4;
typedef __attribute__((ext_vector_type(16))) float f32x16;

typedef __attribute__((address_space(1))) const void glb_cv;
typedef __attribute__((address_space(3))) void lds_v;

__device__ inline ushortT f2bf(float f) {
    return __builtin_bit_cast(ushortT, (__bf16)f);
}

__device__ inline float bf2f(ushortT u) {
    return __builtin_bit_cast(float, (u32)u << 16);
}

__device__ inline u32 pk2bf(float a, float b) {
    return (u32)__builtin_bit_cast(ushortT, (__bf16)a)
         | ((u32)__builtin_bit_cast(ushortT, (__bf16)b) << 16);
}

__device__ inline void gload_lds16(const void* g, void* l) {
    __builtin_amdgcn_global_load_lds((glb_cv*)g, (lds_v*)l, 16, 0, 0);
}

// ---------------------------------------------------------------------------
// convert x fp32 -> bf16, 8 el/thread
// ---------------------------------------------------------------------------
__global__ __launch_bounds__(256)
void convert_f32_bf16(const float* __restrict__ in, ushortT* __restrict__ out)
{
    const size_t i = ((size_t)blockIdx.x * 256 + threadIdx.x) * 8;
    float4 a = *(const float4*)(in + i);
    float4 b = *(const float4*)(in + i + 4);
    union { ushortT u[8]; float4 f; } o;
    o.u[0] = f2bf(a.x); o.u[1] = f2bf(a.y); o.u[2] = f2bf(a.z); o.u[3] = f2bf(a.w);
    o.u[4] = f2bf(b.x); o.u[5] = f2bf(b.y); o.u[6] = f2bf(b.z); o.u[7] = f2bf(b.w);
    *(float4*)(out + i) = o.f;
}

// ---------------------------------------------------------------------------
// scale mask by log2e (exp2-domain)
// ---------------------------------------------------------------------------
__global__ __launch_bounds__(256)
void scale_mask(const float* __restrict__ in, float* __restrict__ outp)
{
    const int i = blockIdx.x * 256 + threadIdx.x;
    outp[i] = in[i] * LOG2E_;
}

// ---------------------------------------------------------------------------
// transpose+convert W [768,768] f32 -> Wt bf16 (Wt[n][k] = W[k][n]).
// ---------------------------------------------------------------------------
__global__ __launch_bounds__(256)
void transpose_w(const float* __restrict__ W0, const float* __restrict__ W1,
                 const float* __restrict__ W2, const float* __restrict__ W3,
                 ushortT* __restrict__ wt4)
{
    const float* W = (blockIdx.z == 0) ? W0 : (blockIdx.z == 1) ? W1
                   : (blockIdx.z == 2) ? W2 : W3;
    ushortT* o = wt4 + (size_t)blockIdx.z * 768 * 768;
    __shared__ float T[64][65];
    const int tid = threadIdx.x;
    const int k0 = blockIdx.x * 64, n0 = blockIdx.y * 64;

    for (int t = tid; t < 1024; t += 256) {
        const int r = t >> 4, c4 = (t & 15) << 2;
        float4 v = *(const float4*)&W[(size_t)(k0 + r) * 768 + n0 + c4];
        T[r][c4 + 0] = v.x; T[r][c4 + 1] = v.y;
        T[r][c4 + 2] = v.z; T[r][c4 + 3] = v.w;
    }
    __syncthreads();
    for (int t = tid; t < 1024; t += 256) {
        const int r = t >> 4, c4 = (t & 15) << 2;
        union { ushortT u[4]; unsigned long long v; } ov;
        ov.u[0] = f2bf(T[c4 + 0][r]); ov.u[1] = f2bf(T[c4 + 1][r]);
        ov.u[2] = f2bf(T[c4 + 2][r]); ov.u[3] = f2bf(T[c4 + 3][r]);
        *(unsigned long long*)&o[(size_t)(n0 + r) * 768 + k0 + c4] = ov.v;
    }
}

// ---------------------------------------------------------------------------
// MFMA GEMM core: C[128x64] = A[m0..,768] * Bt[n0..,768]^T  (bf16, fp32 acc)
// ---------------------------------------------------------------------------
__device__ inline void gemm_core_128x64(
    const ushortT* __restrict__ A, const ushortT* __restrict__ Bt,
    ushortT* As, ushortT* Bs, int m0, int n0, f32x4 acc[4][2])
{
    const int tid  = threadIdx.x;
    const int lane = tid & 63;
    const int wave = tid >> 6;
    const int lr = lane & 15, lg = lane >> 4;
    const int wr = wave >> 1, wc = wave & 1;

    #pragma unroll
    for (int mi = 0; mi < 4; ++mi)
        #pragma unroll
        for (int ni = 0; ni < 2; ++ni)
            acc[mi][ni] = (f32x4){0.f, 0.f, 0.f, 0.f};

    #pragma unroll 1
    for (int k0 = 0; k0 < 768; k0 += 64) {
        __syncthreads();
        #pragma unroll
        for (int it = 0; it < 4; ++it) {
            const int ci = it * 256 + tid;
            const int row = ci >> 3, c = ci & 7;
            const int sc = c ^ (row & 7);
            gload_lds16(A + (size_t)(m0 + row) * 768 + k0 + sc * 8,
                        As + (size_t)(it * 256 + wave * 64) * 8);
        }
        #pragma unroll
        for (int it = 0; it < 2; ++it) {
            const int ci = it * 256 + tid;
            const int row = ci >> 3, c = ci & 7;
            const int sc = c ^ (row & 7);
            gload_lds16(Bt + (size_t)(n0 + row) * 768 + k0 + sc * 8,
                        Bs + (size_t)(it * 256 + wave * 64) * 8);
        }
        __syncthreads();

        #pragma unroll
        for (int ks = 0; ks < 2; ++ks) {
            bf16x8 af[4], bfr[2];
            #pragma unroll
            for (int mi = 0; mi < 4; ++mi) {
                const int row = wr * 64 + mi * 16 + lr;
                const int ch = (ks * 4 + lg) ^ (row & 7);
                af[mi] = __builtin_bit_cast(bf16x8, *(const float4*)(As + row * 64 + ch * 8));
            }
            #pragma unroll
            for (int ni = 0; ni < 2; ++ni) {
                const int row = wc * 32 + ni * 16 + lr;
                const int ch = (ks * 4 + lg) ^ (row & 7);
                bfr[ni] = __builtin_bit_cast(bf16x8, *(const float4*)(Bs + row * 64 + ch * 8));
            }
            #pragma unroll
            for (int mi = 0; mi < 4; ++mi)
                #pragma unroll
                for (int ni = 0; ni < 2; ++ni)
                    acc[mi][ni] = __builtin_amdgcn_mfma_f32_16x16x32_bf16(
                        af[mi], bfr[ni], acc[mi][ni], 0, 0, 0);
        }
    }
}

// ---------------------------------------------------------------------------
// QKV fused GEMM: z in {Q,K,V}. Q/K -> bf16 split-head [B,H,S,HD] (Q scaled
// by SCALE*log2e); V -> written DIRECTLY transposed as Vt [B,H,HD,S].
// ---------------------------------------------------------------------------
__global__ __launch_bounds__(256)
void qkv_gemm(const ushortT* __restrict__ xb, const ushortT* __restrict__ wt4,
              const float* __restrict__ bq, const float* __restrict__ bk,
              const float* __restrict__ bv,
              ushortT* __restrict__ qb, ushortT* __restrict__ kb,
              ushortT* __restrict__ vtb)
{
    __shared__ __align__(16) ushortT As[128 * 64];
    __shared__ __align__(16) ushortT Bs[64 * 64];
    const int z = blockIdx.z;
    const ushortT* Wt = wt4 + (size_t)z * 768 * 768;
    const float* bias = (z == 0) ? bq : (z == 1) ? bk : bv;
    const float scale = (z == 0) ? (SCALE_ * LOG2E_) : 1.0f;

    const int m0 = blockIdx.x * 128, n0 = blockIdx.y * 64;
    f32x4 acc[4][2];
    gemm_core_128x64(xb, Wt, As, Bs, m0, n0, acc);

    const int tid = threadIdx.x;
    const int lane = tid & 63, wave = tid >> 6;
    const int lr = lane & 15, lg = lane >> 4;
    const int wr = wave >> 1, wc = wave & 1;
    const int h = n0 >> 6;

    if (z == 2) {
        #pragma unroll
        for (int ni = 0; ni < 2; ++ni) {
            const int nn = wc * 32 + ni * 16 + lr;
            const float bb = bias[n0 + nn];
            #pragma unroll
            for (int mi = 0; mi < 4; ++mi) {
                const int mb = m0 + wr * 64 + mi * 16 + lg * 4;
                const int b = mb >> 11, s = mb & 2047;
                ushort4 ov;
                ov.x = f2bf(acc[mi][ni][0] + bb);
                ov.y = f2bf(acc[mi][ni][1] + bb);
                ov.z = f2bf(acc[mi][ni][2] + bb);
                ov.w = f2bf(acc[mi][ni][3] + bb);
                *(ushort4*)&vtb[(((size_t)b * H_ + h) * HD_ + nn) * S_ + s] = ov;
            }
        }
    } else {
        ushortT* out = (z == 0) ? qb : kb;
        #pragma unroll
        for (int ni = 0; ni < 2; ++ni) {
            const int nn = wc * 32 + ni * 16 + lr;
            const float bb = bias[n0 + nn];
            #pragma unroll
            for (int mi = 0; mi < 4; ++mi) {
                #pragma unroll
                for (int j = 0; j < 4; ++j) {
                    const int m = m0 + wr * 64 + mi * 16 + lg * 4 + j;
                    const int b = m >> 11, s = m & 2047;
                    out[(((size_t)b * H_ + h) * S_ + s) * HD_ + nn] =
                        f2bf((acc[mi][ni][j] + bb) * scale);
                }
            }
        }
    }
}

// ---------------------------------------------------------------------------
// Output projection: ab bf16 [M,768] x Wo^T -> fp32 [M,768] + bias.
// ---------------------------------------------------------------------------
__global__ __launch_bounds__(256)
void o_gemm(const ushortT* __restrict__ ab, const ushortT* __restrict__ wto,
            const float* __restrict__ bo, float* __restrict__ out)
{
    __shared__ __align__(16) ushortT As[128 * 64];
    __shared__ __align__(16) ushortT Bs[64 * 64];
    const int m0 = blockIdx.x * 128, n0 = blockIdx.y * 64;
    f32x4 acc[4][2];
    gemm_core_128x64(ab, wto, As, Bs, m0, n0, acc);

    const int tid = threadIdx.x;
    const int lane = tid & 63, wave = tid >> 6;
    const int lr = lane & 15, lg = lane >> 4;
    const int wr = wave >> 1, wc = wave & 1;

    #pragma unroll
    for (int ni = 0; ni < 2; ++ni) {
        const int n = n0 + wc * 32 + ni * 16 + lr;
        const float bb = bo[n];
        #pragma unroll
        for (int mi = 0; mi < 4; ++mi) {
            #pragma unroll
            for (int j = 0; j < 4; ++j) {
                const int m = m0 + wr * 64 + mi * 16 + lg * 4 + j;
                out[(size_t)m * 768 + n] = acc[mi][ni][j] + bb;
            }
        }
    }
}

// ---------------------------------------------------------------------------
// Flash attention, 32x32x16 MFMA, KVBLK=32 + KEY-SPLIT x2 for occupancy:
// 2-buffer LDS = 16 KB -> 6 blocks/CU resident (grid 1536) = 24 waves/CU.
// Swapped QK^T (C[key][q], col=q), fixed-max exp2 softmax, mask in C-init;
// P in registers via pk2bf + v_permlane32_swap_b32 (vdst[32:63]<->vsrc[0:31]);
// l-sum via ones-MFMA over the SAME bf16-rounded p as the numerator.
// Each block: 128 q x 1024 keys (32 tiles of 32) -> partial bf16 numerator +
// fp32 denominator; combine() divides (round-11/14-verified numerics).
// Block = 256 thr = 4 waves, 32 q/wave. Grid: 1536 XCD-clustered.
// ---------------------------------------------------------------------------
__global__ __launch_bounds__(256, 6)
void attn_mfma(const ushortT* __restrict__ Q, const ushortT* __restrict__ K,
               const ushortT* __restrict__ Vt, const float* __restrict__ msc,
               ushortT* __restrict__ pn, float* __restrict__ pl)
{
    __shared__ __align__(16) ushortT Ks[2][32 * 64];   // 4 KB each
    __shared__ __align__(16) ushortT Vs[2][64 * 32];   // 4 KB each (row=hd,64B)

    const int tid  = threadIdx.x;
    const int lane = tid & 63;
    const int wq   = tid >> 6;       // 0..3
    const int col  = lane & 31;      // q-col / key-row / hd-row selector
    const int hi   = lane >> 5;

    // XCD-clustered decode: 8 XCDs x 6 bh x (16 q-blocks x 2 key-halves)
    const int gid  = blockIdx.x;
    const int xcd  = gid & 7;
    const int w    = gid >> 3;               // 0..191
    const int bh_i = xcd * 6 + (w >> 5);     // 0..47
    const int r5   = w & 31;
    const int q0   = (r5 >> 1) * 128;
    const int kh   = r5 & 1;                 // key half
    const int b    = bh_i / H_;
    const int h    = bh_i % H_;
    const size_t bh = (size_t)bh_i;

    // Q B-fragments: col=q, k = ks*16 + 8*hi + i  (32 q per wave)
    bf16x8 qf[4];
    {
        const ushortT* Qg = Q + (bh * S_ + q0 + wq * 32 + col) * HD_;
        #pragma unroll
        for (int ks = 0; ks < 4; ++ks)
            qf[ks] = __builtin_bit_cast(bf16x8,
                *(const float4*)(Qg + ks * 16 + hi * 8));
    }

    const ushortT* Kg = K  + bh * S_ * HD_ + (size_t)kh * 1024 * HD_;
    const ushortT* Vg = Vt + bh * HD_ * S_ + (size_t)kh * 1024;
    const float*   mg = msc + (size_t)b * S_ + (size_t)kh * 1024;

    // staging source pointers (pre-swizzled), advanced by const per tile.
    // K tile 32x64 (rows 128B, 8 chunks): lane writes row=tid>>3, chunk=tid&7.
    // V tile 64x32 (rows 64B, 4 chunks):  lane writes row=tid>>2, chunk=tid&3.
    const ushortT* ksrc;
    const ushortT* vsrc;
    {
        const int kr = tid >> 3, kc = tid & 7, ksc = kc ^ (kr & 7);
        ksrc = Kg + (size_t)kr * HD_ + ksc * 8;
        const int vr = tid >> 2, vc = tid & 3, vsc = vc ^ (vr & 3);
        vsrc = Vg + (size_t)vr * S_ + vsc * 8;
    }

    // loop-invariant LDS read byte-offsets (swizzled)
    int ko[4], vo[2][2];
    {
        const int r = col;                     // key row 0..31
        #pragma unroll
        for (int ks = 0; ks < 4; ++ks)
            ko[ks] = r * 128 + (((2 * ks + hi) ^ (r & 7)) << 4);
    }
    #pragma unroll
    for (int hb = 0; hb < 2; ++hb) {
        const int r = hb * 32 + col;           // hd row 0..63
        #pragma unroll
        for (int sg = 0; sg < 2; ++sg)
            vo[hb][sg] = r * 64 + (((2 * sg + hi) ^ (r & 3)) << 4);
    }

    // ones A-fragment for the l-sum MFMA
    bf16x8 onesA;
    #pragma unroll
    for (int i = 0; i < 8; ++i) onesA[i] = (__bf16)1.0f;

    f32x16 acc[2];       // [hd-block]: lane q = col
    f32x16 accl;         // l-sum (every reg = full row sum for col q)
    #pragma unroll
    for (int hb = 0; hb < 2; ++hb)
        #pragma unroll
        for (int r = 0; r < 16; ++r) acc[hb][r] = 0.f;
    #pragma unroll
    for (int r = 0; r < 16; ++r) accl[r] = 0.f;

    auto stage = [&](int bsel) {   // 2 gload_lds per wave (K 1KB + V 1KB)
        gload_lds16(ksrc, &Ks[bsel][(size_t)wq * 512]);
        ksrc += 32 * HD_;
        gload_lds16(vsrc, &Vs[bsel][(size_t)wq * 512]);
        vsrc += 32;
    };

    stage(0);
    __syncthreads();

    for (int kt = 0; kt < 32; ++kt) {
        const int buf = kt & 1;
        if (kt + 1 < 32) stage(buf ^ 1);

        // mask C-init: C reg r <-> key row (r&3)+8*(r>>2)+4*hi
        f32x16 s;
        #pragma unroll
        for (int g = 0; g < 4; ++g) {
            float4 mv = *(const float4*)(mg + kt * 32 + g * 8 + hi * 4);
            s[4 * g + 0] = mv.x;
            s[4 * g + 1] = mv.y;
            s[4 * g + 2] = mv.z;
            s[4 * g + 3] = mv.w;
        }

        // ---- QK^T swapped, C = mask ----
        __builtin_amdgcn_s_setprio(1);
        #pragma unroll
        for (int ks = 0; ks < 4; ++ks) {
            bf16x8 kf = __builtin_bit_cast(bf16x8,
                *(const float4*)((const char*)&Ks[buf][0] + ko[ks]));
            s = __builtin_amdgcn_mfma_f32_32x32x16_bf16(
                kf, qf[ks], s, 0, 0, 0);
        }
        __builtin_amdgcn_s_setprio(0);

        // ---- p = 2^s; pack into PV B-frags via permlane swap ----
        float p[16];
        #pragma unroll
        for (int r = 0; r < 16; ++r) p[r] = exp2f(s[r]);

        u32 bw[2][4];
        #pragma unroll
        for (int sl = 0; sl < 2; ++sl) {
            u32 u0 = pk2bf(p[8 * sl + 0], p[8 * sl + 1]);
            u32 u1 = pk2bf(p[8 * sl + 2], p[8 * sl + 3]);
            u32 v0 = pk2bf(p[8 * sl + 4], p[8 * sl + 5]);
            u32 v1 = pk2bf(p[8 * sl + 6], p[8 * sl + 7]);
            // swap semantics: vdst[32:63] <-> vsrc[0:31]
            asm("v_permlane32_swap_b32 %0, %1" : "+v"(u0), "+v"(v0));
            asm("v_permlane32_swap_b32 %0, %1" : "+v"(u1), "+v"(v1));
            bw[sl][0] = u0; bw[sl][1] = u1;
            bw[sl][2] = v0; bw[sl][3] = v1;
        }

        // ---- PV + l-sum: acc[hd][q] += V^T x P^T; accl += 1 x P^T ----
        __builtin_amdgcn_s_setprio(1);
        #pragma unroll
        for (int sg = 0; sg < 2; ++sg) {
            union { u32 w[4]; bf16x8 v; } pb;
            pb.w[0] = bw[sg][0]; pb.w[1] = bw[sg][1];
            pb.w[2] = bw[sg][2]; pb.w[3] = bw[sg][3];
            #pragma unroll
            for (int hb = 0; hb < 2; ++hb) {
                bf16x8 vf = __builtin_bit_cast(bf16x8,
                    *(const float4*)((const char*)&Vs[buf][0] + vo[hb][sg]));
                acc[hb] = __builtin_amdgcn_mfma_f32_32x32x16_bf16(
                    vf, pb.v, acc[hb], 0, 0, 0);
            }
            accl = __builtin_amdgcn_mfma_f32_32x32x16_bf16(
                onesA, pb.v, accl, 0, 0, 0);
        }
        __builtin_amdgcn_s_setprio(0);

        __syncthreads();   // drains prefetch DMA; swap buffers
    }

    // ---- epilogue: PARTIAL outputs (no divide). lane q = col ----
    ushortT* pnh = pn + (size_t)kh * NE_;
    float*   plh = pl + (size_t)kh * BHS_;
    const int q = q0 + wq * 32 + col;
    const size_t row = (size_t)b * S_ + q;
    plh[bh * S_ + q] = accl[0];     // hi=0/1 lanes write the same value
    #pragma unroll
    for (int hb = 0; hb < 2; ++hb) {
        #pragma unroll
        for (int t = 0; t < 4; ++t) {
            ushort4 ov;
            ov.x = f2bf(acc[hb][4 * t + 0]);
            ov.y = f2bf(acc[hb][4 * t + 1]);
            ov.z = f2bf(acc[hb][4 * t + 2]);
            ov.w = f2bf(acc[hb][4 * t + 3]);
            *(ushort4*)&pnh[row * D_ + h * HD_ + hb * 32 + t * 8 + hi * 4] = ov;
        }
    }
}

// ---------------------------------------------------------------------------
// combine: ab[q,d] = (pn0[q,d] + pn1[q,d]) / (pl0[q,h] + pl1[q,h]), bf16.
// ---------------------------------------------------------------------------
__global__ __launch_bounds__(256)
void combine(const ushortT* __restrict__ pn, const float* __restrict__ pl,
             ushortT* __restrict__ ab)
{
    const size_t i8 = ((size_t)blockIdx.x * 256 + threadIdx.x) * 8;
    const int d   = (int)(i8 % D_);         // 8-aligned, within one head
    const size_t row = i8 / D_;             // b*S + s
    const int hh  = d >> 6;
    const int b   = (int)(row >> 11);
    const int s   = (int)(row & 2047);
    const size_t li = ((size_t)b * H_ + hh) * S_ + s;
    const float inv = 1.f / (pl[li] + pl[BHS_ + li]);

    union { ushortT u[8]; float4 f; } a, c, o;
    a.f = *(const float4*)(pn + i8);
    c.f = *(const float4*)(pn + NE_ + i8);
    #pragma unroll
    for (int j = 0; j < 8; ++j)
        o.u[j] = f2bf((bf2f(a.u[j]) + bf2f(c.u[j])) * inv);
    *(float4*)(ab + i8) = o.f;
}

// ---------------------------------------------------------------------------
extern "C" void kernel_launch(void* const* d_in, const int* in_sizes, int n_in,
                              void* d_out, int out_size, void* d_ws, size_t ws_size,
                              hipStream_t stream)
{
    const float* x    = (const float*)d_in[0];
    const float* mask = (const float*)d_in[1];
    const float* Wq   = (const float*)d_in[2];
    const float* bq   = (const float*)d_in[3];
    const float* Wk   = (const float*)d_in[4];
    const float* bk   = (const float*)d_in[5];
    const float* Wv   = (const float*)d_in[6];
    const float* bv   = (const float*)d_in[7];
    const float* Wo   = (const float*)d_in[8];
    const float* bo   = (const float*)d_in[9];
    float* out = (float*)d_out;

    ushortT* xb  = (ushortT*)d_ws;           // NE (reused as ab)
    ushortT* qb  = xb + NE_;
    ushortT* kb  = qb + NE_;
    ushortT* vtb = kb + NE_;
    ushortT* pn  = vtb + NE_;                // 2 * NE partial numerators
    ushortT* wt4 = pn + 2 * NE_;             // 4 * 768 * 768
    float*   msc = (float*)(wt4 + (size_t)4 * 768 * 768);  // B*S
    float*   pl  = msc + (size_t)B_ * S_;    // 2 * BHS partial denominators
    ushortT* ab  = xb;                       // alias: xb free after qkv_gemm

    convert_f32_bf16<<<NE_ / 2048, 256, 0, stream>>>(x, xb);
    scale_mask<<<(B_ * S_) / 256, 256, 0, stream>>>(mask, msc);
    transpose_w<<<dim3(12, 12, 4), 256, 0, stream>>>(Wq, Wk, Wv, Wo, wt4);

    qkv_gemm<<<dim3(M_ / 128, 12, 3), 256, 0, stream>>>(
        xb, wt4, bq, bk, bv, qb, kb, vtb);

    attn_mfma<<<1536, 256, 0, stream>>>(qb, kb, vtb, msc, pn, pl);

    combine<<<NE_ / 2048, 256, 0, stream>>>(pn, pl, ab);

    o_gemm<<<dim3(M_ / 128, 12), 256, 0, stream>>>(
        ab, wt4 + (size_t)3 * 768 * 768, bo, out);
}

// Round 17
// 171.173 us; speedup vs baseline: 1.6897x; 1.6897x over previous
//
#include <hip/hip_runtime.h>
#include <cmath>

#define B_ 4
#define S_ 2048
#define D_ 768
#define H_ 12
#define HD_ 64
#define SCALE_ 0.125f
#define LOG2E_ 1.4426950408889634f
#define M_ 8192
#define NE_ 6291456ull   // B*S*D

typedef unsigned short ushortT;
typedef unsigned int u32;
typedef __attribute__((ext_vector_type(8))) __bf16 bf16x8;
typedef __attribute__((ext_vector_type(4))) float f32x4;
typedef __attribute__((ext_vector_type(16))) float f32x16;

typedef __attribute__((address_space(1))) const void glb_cv;
typedef __attribute__((address_space(3))) void lds_v;

__device__ inline ushortT f2bf(float f) {
    return __builtin_bit_cast(ushortT, (__bf16)f);
}

__device__ inline u32 pk2bf(float a, float b) {
    return (u32)__builtin_bit_cast(ushortT, (__bf16)a)
         | ((u32)__builtin_bit_cast(ushortT, (__bf16)b) << 16);
}

__device__ inline void gload_lds16(const void* g, void* l) {
    __builtin_amdgcn_global_load_lds((glb_cv*)g, (lds_v*)l, 16, 0, 0);
}

// ---------------------------------------------------------------------------
// convert x fp32 -> bf16, 8 el/thread
// ---------------------------------------------------------------------------
__global__ __launch_bounds__(256)
void convert_f32_bf16(const float* __restrict__ in, ushortT* __restrict__ out)
{
    const size_t i = ((size_t)blockIdx.x * 256 + threadIdx.x) * 8;
    float4 a = *(const float4*)(in + i);
    float4 b = *(const float4*)(in + i + 4);
    union { ushortT u[8]; float4 f; } o;
    o.u[0] = f2bf(a.x); o.u[1] = f2bf(a.y); o.u[2] = f2bf(a.z); o.u[3] = f2bf(a.w);
    o.u[4] = f2bf(b.x); o.u[5] = f2bf(b.y); o.u[6] = f2bf(b.z); o.u[7] = f2bf(b.w);
    *(float4*)(out + i) = o.f;
}

// ---------------------------------------------------------------------------
// scale mask by log2e (exp2-domain)
// ---------------------------------------------------------------------------
__global__ __launch_bounds__(256)
void scale_mask(const float* __restrict__ in, float* __restrict__ outp)
{
    const int i = blockIdx.x * 256 + threadIdx.x;
    outp[i] = in[i] * LOG2E_;
}

// ---------------------------------------------------------------------------
// transpose+convert W [768,768] f32 -> Wt bf16 (Wt[n][k] = W[k][n]).
// ---------------------------------------------------------------------------
__global__ __launch_bounds__(256)
void transpose_w(const float* __restrict__ W0, const float* __restrict__ W1,
                 const float* __restrict__ W2, const float* __restrict__ W3,
                 ushortT* __restrict__ wt4)
{
    const float* W = (blockIdx.z == 0) ? W0 : (blockIdx.z == 1) ? W1
                   : (blockIdx.z == 2) ? W2 : W3;
    ushortT* o = wt4 + (size_t)blockIdx.z * 768 * 768;
    __shared__ float T[64][65];
    const int tid = threadIdx.x;
    const int k0 = blockIdx.x * 64, n0 = blockIdx.y * 64;

    for (int t = tid; t < 1024; t += 256) {
        const int r = t >> 4, c4 = (t & 15) << 2;
        float4 v = *(const float4*)&W[(size_t)(k0 + r) * 768 + n0 + c4];
        T[r][c4 + 0] = v.x; T[r][c4 + 1] = v.y;
        T[r][c4 + 2] = v.z; T[r][c4 + 3] = v.w;
    }
    __syncthreads();
    for (int t = tid; t < 1024; t += 256) {
        const int r = t >> 4, c4 = (t & 15) << 2;
        union { ushortT u[4]; unsigned long long v; } ov;
        ov.u[0] = f2bf(T[c4 + 0][r]); ov.u[1] = f2bf(T[c4 + 1][r]);
        ov.u[2] = f2bf(T[c4 + 2][r]); ov.u[3] = f2bf(T[c4 + 3][r]);
        *(unsigned long long*)&o[(size_t)(n0 + r) * 768 + k0 + c4] = ov.v;
    }
}

// ---------------------------------------------------------------------------
// MFMA GEMM core: C[128x64] = A[m0..,768] * Bt[n0..,768]^T  (bf16, fp32 acc)
// ---------------------------------------------------------------------------
__device__ inline void gemm_core_128x64(
    const ushortT* __restrict__ A, const ushortT* __restrict__ Bt,
    ushortT* As, ushortT* Bs, int m0, int n0, f32x4 acc[4][2])
{
    const int tid  = threadIdx.x;
    const int lane = tid & 63;
    const int wave = tid >> 6;
    const int lr = lane & 15, lg = lane >> 4;
    const int wr = wave >> 1, wc = wave & 1;

    #pragma unroll
    for (int mi = 0; mi < 4; ++mi)
        #pragma unroll
        for (int ni = 0; ni < 2; ++ni)
            acc[mi][ni] = (f32x4){0.f, 0.f, 0.f, 0.f};

    #pragma unroll 1
    for (int k0 = 0; k0 < 768; k0 += 64) {
        __syncthreads();
        #pragma unroll
        for (int it = 0; it < 4; ++it) {
            const int ci = it * 256 + tid;
            const int row = ci >> 3, c = ci & 7;
            const int sc = c ^ (row & 7);
            gload_lds16(A + (size_t)(m0 + row) * 768 + k0 + sc * 8,
                        As + (size_t)(it * 256 + wave * 64) * 8);
        }
        #pragma unroll
        for (int it = 0; it < 2; ++it) {
            const int ci = it * 256 + tid;
            const int row = ci >> 3, c = ci & 7;
            const int sc = c ^ (row & 7);
            gload_lds16(Bt + (size_t)(n0 + row) * 768 + k0 + sc * 8,
                        Bs + (size_t)(it * 256 + wave * 64) * 8);
        }
        __syncthreads();

        #pragma unroll
        for (int ks = 0; ks < 2; ++ks) {
            bf16x8 af[4], bfr[2];
            #pragma unroll
            for (int mi = 0; mi < 4; ++mi) {
                const int row = wr * 64 + mi * 16 + lr;
                const int ch = (ks * 4 + lg) ^ (row & 7);
                af[mi] = __builtin_bit_cast(bf16x8, *(const float4*)(As + row * 64 + ch * 8));
            }
            #pragma unroll
            for (int ni = 0; ni < 2; ++ni) {
                const int row = wc * 32 + ni * 16 + lr;
                const int ch = (ks * 4 + lg) ^ (row & 7);
                bfr[ni] = __builtin_bit_cast(bf16x8, *(const float4*)(Bs + row * 64 + ch * 8));
            }
            #pragma unroll
            for (int mi = 0; mi < 4; ++mi)
                #pragma unroll
                for (int ni = 0; ni < 2; ++ni)
                    acc[mi][ni] = __builtin_amdgcn_mfma_f32_16x16x32_bf16(
                        af[mi], bfr[ni], acc[mi][ni], 0, 0, 0);
        }
    }
}

// ---------------------------------------------------------------------------
// QKV fused GEMM: z in {Q,K,V}. Q/K -> bf16 split-head [B,H,S,HD] (Q scaled
// by SCALE*log2e); V -> written DIRECTLY transposed as Vt [B,H,HD,S].
// ---------------------------------------------------------------------------
__global__ __launch_bounds__(256)
void qkv_gemm(const ushortT* __restrict__ xb, const ushortT* __restrict__ wt4,
              const float* __restrict__ bq, const float* __restrict__ bk,
              const float* __restrict__ bv,
              ushortT* __restrict__ qb, ushortT* __restrict__ kb,
              ushortT* __restrict__ vtb)
{
    __shared__ __align__(16) ushortT As[128 * 64];
    __shared__ __align__(16) ushortT Bs[64 * 64];
    const int z = blockIdx.z;
    const ushortT* Wt = wt4 + (size_t)z * 768 * 768;
    const float* bias = (z == 0) ? bq : (z == 1) ? bk : bv;
    const float scale = (z == 0) ? (SCALE_ * LOG2E_) : 1.0f;

    const int m0 = blockIdx.x * 128, n0 = blockIdx.y * 64;
    f32x4 acc[4][2];
    gemm_core_128x64(xb, Wt, As, Bs, m0, n0, acc);

    const int tid = threadIdx.x;
    const int lane = tid & 63, wave = tid >> 6;
    const int lr = lane & 15, lg = lane >> 4;
    const int wr = wave >> 1, wc = wave & 1;
    const int h = n0 >> 6;

    if (z == 2) {
        #pragma unroll
        for (int ni = 0; ni < 2; ++ni) {
            const int nn = wc * 32 + ni * 16 + lr;
            const float bb = bias[n0 + nn];
            #pragma unroll
            for (int mi = 0; mi < 4; ++mi) {
                const int mb = m0 + wr * 64 + mi * 16 + lg * 4;
                const int b = mb >> 11, s = mb & 2047;
                ushort4 ov;
                ov.x = f2bf(acc[mi][ni][0] + bb);
                ov.y = f2bf(acc[mi][ni][1] + bb);
                ov.z = f2bf(acc[mi][ni][2] + bb);
                ov.w = f2bf(acc[mi][ni][3] + bb);
                *(ushort4*)&vtb[(((size_t)b * H_ + h) * HD_ + nn) * S_ + s] = ov;
            }
        }
    } else {
        ushortT* out = (z == 0) ? qb : kb;
        #pragma unroll
        for (int ni = 0; ni < 2; ++ni) {
            const int nn = wc * 32 + ni * 16 + lr;
            const float bb = bias[n0 + nn];
            #pragma unroll
            for (int mi = 0; mi < 4; ++mi) {
                #pragma unroll
                for (int j = 0; j < 4; ++j) {
                    const int m = m0 + wr * 64 + mi * 16 + lg * 4 + j;
                    const int b = m >> 11, s = m & 2047;
                    out[(((size_t)b * H_ + h) * S_ + s) * HD_ + nn] =
                        f2bf((acc[mi][ni][j] + bb) * scale);
                }
            }
        }
    }
}

// ---------------------------------------------------------------------------
// Output projection: ab bf16 [M,768] x Wo^T -> fp32 [M,768] + bias.
// ---------------------------------------------------------------------------
__global__ __launch_bounds__(256)
void o_gemm(const ushortT* __restrict__ ab, const ushortT* __restrict__ wto,
            const float* __restrict__ bo, float* __restrict__ out)
{
    __shared__ __align__(16) ushortT As[128 * 64];
    __shared__ __align__(16) ushortT Bs[64 * 64];
    const int m0 = blockIdx.x * 128, n0 = blockIdx.y * 64;
    f32x4 acc[4][2];
    gemm_core_128x64(ab, wto, As, Bs, m0, n0, acc);

    const int tid = threadIdx.x;
    const int lane = tid & 63, wave = tid >> 6;
    const int lr = lane & 15, lg = lane >> 4;
    const int wr = wave >> 1, wc = wave & 1;

    #pragma unroll
    for (int ni = 0; ni < 2; ++ni) {
        const int n = n0 + wc * 32 + ni * 16 + lr;
        const float bb = bo[n];
        #pragma unroll
        for (int mi = 0; mi < 4; ++mi) {
            #pragma unroll
            for (int j = 0; j < 4; ++j) {
                const int m = m0 + wr * 64 + mi * 16 + lg * 4 + j;
                out[(size_t)m * 768 + n] = acc[mi][ni][j] + bb;
            }
        }
    }
}

// ---------------------------------------------------------------------------
// Flash attention, 32x32x16 MFMA (round-12 configuration — best measured).
// Swapped QK^T (C[key][q], col=q), fixed-max exp2 softmax, mask in MFMA
// C-init. P in registers via pk2bf + v_permlane32_swap_b32
// (vdst[32:63] <-> vsrc[0:31]). l-sum via ones-MFMA over the SAME
// bf16-rounded p as the numerator (rounding cancels in p/Σp).
// Block = 256 thr = 4 waves; 32 q/wave (128 q/block); KV tiles of 64,
// double-buffered via global_load_lds. Grid: 768 blocks, XCD-clustered;
// 3 blocks/CU x 4 waves = 12 waves/CU, VGPR 64, LDS 32KB.
// ---------------------------------------------------------------------------
__global__ __launch_bounds__(256, 3)
void attn_mfma(const ushortT* __restrict__ Q, const ushortT* __restrict__ K,
               const ushortT* __restrict__ Vt, const float* __restrict__ msc,
               ushortT* __restrict__ out)
{
    __shared__ __align__(16) ushortT Ks[2][64 * 64];
    __shared__ __align__(16) ushortT Vs[2][64 * 64];

    const int tid  = threadIdx.x;
    const int lane = tid & 63;
    const int wq   = tid >> 6;       // 0..3
    const int col  = lane & 31;      // q-col / key-row / hd-row selector
    const int hi   = lane >> 5;

    // XCD-clustered decode: 8 XCDs x 6 bh x 16 q-blocks of 128
    const int gid  = blockIdx.x;
    const int xcd  = gid & 7;
    const int w    = gid >> 3;
    const int bh_i = xcd * 6 + (w >> 4);
    const int q0   = (w & 15) * 128;
    const int b    = bh_i / H_;
    const int h    = bh_i % H_;
    const size_t bh = (size_t)bh_i;

    // Q B-fragments: col=q, k = ks*16 + 8*hi + i  (32 q per wave)
    bf16x8 qf[4];
    {
        const ushortT* Qg = Q + (bh * S_ + q0 + wq * 32 + col) * HD_;
        #pragma unroll
        for (int ks = 0; ks < 4; ++ks)
            qf[ks] = __builtin_bit_cast(bf16x8,
                *(const float4*)(Qg + ks * 16 + hi * 8));
    }

    const ushortT* Kg = K  + bh * S_ * HD_;
    const ushortT* Vg = Vt + bh * HD_ * S_;
    const float*   mg = msc + (size_t)b * S_;

    // staging source pointers (pre-swizzled), advanced by const per tile
    const ushortT* ksrc[2];
    const ushortT* vsrc[2];
    #pragma unroll
    for (int it = 0; it < 2; ++it) {
        const int ci = it * 256 + tid;
        const int row = ci >> 3, c = ci & 7, sc = c ^ (row & 7);
        ksrc[it] = Kg + (size_t)row * HD_ + sc * 8;
        vsrc[it] = Vg + (size_t)row * S_ + sc * 8;
    }

    // loop-invariant LDS read byte-offsets (swizzled)
    int ko[2][4], vo[2][4];
    #pragma unroll
    for (int kb2 = 0; kb2 < 2; ++kb2) {
        const int r = kb2 * 32 + col;
        #pragma unroll
        for (int ks = 0; ks < 4; ++ks)
            ko[kb2][ks] = r * 128 + (((2 * ks + hi) ^ (r & 7)) << 4);
    }
    #pragma unroll
    for (int hb = 0; hb < 2; ++hb) {
        const int r = hb * 32 + col;
        #pragma unroll
        for (int sg = 0; sg < 4; ++sg)
            vo[hb][sg] = r * 128 + (((2 * sg + hi) ^ (r & 7)) << 4);
    }

    // ones A-fragment for the l-sum MFMA
    bf16x8 onesA;
    #pragma unroll
    for (int i = 0; i < 8; ++i) onesA[i] = (__bf16)1.0f;

    f32x16 acc[2];       // [hd-block]: lane q = col, hd rows per reg map
    f32x16 accl;         // l-sum (every reg = full row sum for col q)
    #pragma unroll
    for (int hb = 0; hb < 2; ++hb)
        #pragma unroll
        for (int r = 0; r < 16; ++r) acc[hb][r] = 0.f;
    #pragma unroll
    for (int r = 0; r < 16; ++r) accl[r] = 0.f;

    auto stage = [&](int bsel) {
        #pragma unroll
        for (int it = 0; it < 2; ++it) {
            gload_lds16(ksrc[it], &Ks[bsel][(it * 256 + wq * 64) * 8]);
            ksrc[it] += 64 * HD_;
        }
        #pragma unroll
        for (int it = 0; it < 2; ++it) {
            gload_lds16(vsrc[it], &Vs[bsel][(it * 256 + wq * 64) * 8]);
            vsrc[it] += 64;
        }
    };

    stage(0);
    __syncthreads();

    for (int kt = 0; kt < S_ / 64; ++kt) {
        const int buf = kt & 1;
        if (kt + 1 < S_ / 64) stage(buf ^ 1);

        u32 bw[4][4];
        #pragma unroll
        for (int kb2 = 0; kb2 < 2; ++kb2) {
            // mask C-init: C reg r <-> key row (r&3)+8*(r>>2)+4*hi
            f32x16 s;
            #pragma unroll
            for (int g = 0; g < 4; ++g) {
                float4 mv = *(const float4*)(mg + kt * 64 + kb2 * 32 + g * 8 + hi * 4);
                s[4 * g + 0] = mv.x;
                s[4 * g + 1] = mv.y;
                s[4 * g + 2] = mv.z;
                s[4 * g + 3] = mv.w;
            }

            // ---- QK^T swapped, C = mask ----
            __builtin_amdgcn_s_setprio(1);
            #pragma unroll
            for (int ks = 0; ks < 4; ++ks) {
                bf16x8 kf = __builtin_bit_cast(bf16x8,
                    *(const float4*)((const char*)&Ks[buf][0] + ko[kb2][ks]));
                s = __builtin_amdgcn_mfma_f32_32x32x16_bf16(
                    kf, qf[ks], s, 0, 0, 0);
            }
            __builtin_amdgcn_s_setprio(0);

            // ---- p = 2^s; pack into PV B-frags via permlane swap ----
            float p[16];
            #pragma unroll
            for (int r = 0; r < 16; ++r) p[r] = exp2f(s[r]);

            #pragma unroll
            for (int sl = 0; sl < 2; ++sl) {
                u32 u0 = pk2bf(p[8 * sl + 0], p[8 * sl + 1]);
                u32 u1 = pk2bf(p[8 * sl + 2], p[8 * sl + 3]);
                u32 v0 = pk2bf(p[8 * sl + 4], p[8 * sl + 5]);
                u32 v1 = pk2bf(p[8 * sl + 6], p[8 * sl + 7]);
                // swap semantics: vdst[32:63] <-> vsrc[0:31]
                asm("v_permlane32_swap_b32 %0, %1" : "+v"(u0), "+v"(v0));
                asm("v_permlane32_swap_b32 %0, %1" : "+v"(u1), "+v"(v1));
                const int sg = kb2 * 2 + sl;
                bw[sg][0] = u0; bw[sg][1] = u1;
                bw[sg][2] = v0; bw[sg][3] = v1;
            }
        }

        // ---- PV + l-sum: acc[hd][q] += V^T x P^T; accl += 1 x P^T ----
        __builtin_amdgcn_s_setprio(1);
        #pragma unroll
        for (int sg = 0; sg < 4; ++sg) {
            union { u32 w[4]; bf16x8 v; } pb;
            pb.w[0] = bw[sg][0]; pb.w[1] = bw[sg][1];
            pb.w[2] = bw[sg][2]; pb.w[3] = bw[sg][3];
            #pragma unroll
            for (int hb = 0; hb < 2; ++hb) {
                bf16x8 vf = __builtin_bit_cast(bf16x8,
                    *(const float4*)((const char*)&Vs[buf][0] + vo[hb][sg]));
                acc[hb] = __builtin_amdgcn_mfma_f32_32x32x16_bf16(
                    vf, pb.v, acc[hb], 0, 0, 0);
            }
            accl = __builtin_amdgcn_mfma_f32_32x32x16_bf16(
                onesA, pb.v, accl, 0, 0, 0);
        }
        __builtin_amdgcn_s_setprio(0);

        __syncthreads();   // drains prefetch DMA; swap buffers
    }

    // ---- epilogue: lane q = col; hd = hb*32 + (r&3)+8*(r>>2)+4*hi ----
    const float inv = 1.f / accl[0];
    const size_t row = (size_t)b * S_ + q0 + wq * 32 + col;
    #pragma unroll
    for (int hb = 0; hb < 2; ++hb) {
        #pragma unroll
        for (int t = 0; t < 4; ++t) {
            ushort4 ov;
            ov.x = f2bf(acc[hb][4 * t + 0] * inv);
            ov.y = f2bf(acc[hb][4 * t + 1] * inv);
            ov.z = f2bf(acc[hb][4 * t + 2] * inv);
            ov.w = f2bf(acc[hb][4 * t + 3] * inv);
            *(ushort4*)&out[row * D_ + h * HD_ + hb * 32 + t * 8 + hi * 4] = ov;
        }
    }
}

// ---------------------------------------------------------------------------
extern "C" void kernel_launch(void* const* d_in, const int* in_sizes, int n_in,
                              void* d_out, int out_size, void* d_ws, size_t ws_size,
                              hipStream_t stream)
{
    const float* x    = (const float*)d_in[0];
    const float* mask = (const float*)d_in[1];
    const float* Wq   = (const float*)d_in[2];
    const float* bq   = (const float*)d_in[3];
    const float* Wk   = (const float*)d_in[4];
    const float* bk   = (const float*)d_in[5];
    const float* Wv   = (const float*)d_in[6];
    const float* bv   = (const float*)d_in[7];
    const float* Wo   = (const float*)d_in[8];
    const float* bo   = (const float*)d_in[9];
    float* out = (float*)d_out;

    ushortT* xb  = (ushortT*)d_ws;
    ushortT* qb  = xb + NE_;
    ushortT* kb  = qb + NE_;
    ushortT* vtb = kb + NE_;
    ushortT* ab  = vtb + NE_;
    ushortT* wt4 = ab + NE_;                 // 4 * 768 * 768
    float*   msc = (float*)(wt4 + (size_t)4 * 768 * 768);  // B*S floats

    convert_f32_bf16<<<NE_ / 2048, 256, 0, stream>>>(x, xb);
    scale_mask<<<(B_ * S_) / 256, 256, 0, stream>>>(mask, msc);
    transpose_w<<<dim3(12, 12, 4), 256, 0, stream>>>(Wq, Wk, Wv, Wo, wt4);

    qkv_gemm<<<dim3(M_ / 128, 12, 3), 256, 0, stream>>>(
        xb, wt4, bq, bk, bv, qb, kb, vtb);

    attn_mfma<<<768, 256, 0, stream>>>(qb, kb, vtb, msc, ab);

    o_gemm<<<dim3(M_ / 128, 12), 256, 0, stream>>>(
        ab, wt4 + (size_t)3 * 768 * 768, bo, out);
}